// Round 6
// baseline (196.735 us; speedup 1.0000x reference)
//
#include <hip/hip_runtime.h>
#include <cstdint>

#define TOKENS 16384
#define DMODEL 512
#define DIM    1024
#define NQ     10
#define NL     2
#define BM     128
#define BN     128
#define BK     32

typedef __bf16 bf16x8 __attribute__((ext_vector_type(8)));
typedef float  f32x4  __attribute__((ext_vector_type(4)));
typedef unsigned short u16x8 __attribute__((ext_vector_type(8)));

__device__ __forceinline__ float b2f(unsigned short h) {
    union { unsigned u; float f; } v; v.u = ((unsigned)h) << 16; return v.f;
}
__device__ __forceinline__ unsigned short f2b(float f) {
    unsigned u = __builtin_bit_cast(unsigned, f);
    return (unsigned short)((u + 0x7FFFu + ((u >> 16) & 1u)) >> 16);  // RNE
}
__device__ __forceinline__ float2 cmul(float2 a, float2 b) {
    return make_float2(a.x * b.x - a.y * b.y, a.x * b.y + a.y * b.x);
}
__device__ __forceinline__ float2 cadd(float2 a, float2 b) {
    return make_float2(a.x + b.x, a.y + b.y);
}
__device__ __forceinline__ void async_copy16(const void* g, void* l) {
    __builtin_amdgcn_global_load_lds((const __attribute__((address_space(1))) void*)g,
                                     (__attribute__((address_space(3))) void*)l, 16, 0, 0);
}

// ---------------------------------------------------------------------------
// prep_all: block-id branched fused prep.
// U-row mapping v2 (lane-local mem-adjacent p-pairs for gemm1's ushort2
// epilogue): Re(c) -> row (c>>5)*64 + (c&1)*32 + ((c>>1)&15), Im(c) -> +16.
// Bijective within each 64-row group; fold/b2 are permutation-invariant.
// ---------------------------------------------------------------------------
__global__ __launch_bounds__(256)
void prep_all_kernel(const float* __restrict__ x,  unsigned short* __restrict__ xb,
                     const float* __restrict__ w2, unsigned short* __restrict__ w2b,
                     const float* __restrict__ W_in, unsigned short* __restrict__ wtT,
                     const float* __restrict__ rot, const float* __restrict__ ent,
                     const float* __restrict__ bin,
                     unsigned short* __restrict__ U, float* __restrict__ b2) {
    const int bid = blockIdx.x;
    const int t = threadIdx.x;

    if (bid < 256) {
        // ---------------- buildU + b2 ----------------
        __shared__ float2 Gs[NL * NQ * 4];
        const int lane = t & 63;
        const int c = bid * 4 + (t >> 6);

        if (t < NL * NQ) {
            float tx = rot[t * 3 + 0] * 0.5f;
            float ty = rot[t * 3 + 1] * 0.5f;
            float tz = rot[t * 3 + 2] * 0.5f;
            float cx = cosf(tx), sx = sinf(tx);
            float cy = cosf(ty), sy = sinf(ty);
            float cz = cosf(tz), sz = sinf(tz);
            float2 rx00 = make_float2(cx, 0.f),  rx01 = make_float2(0.f, -sx);
            float2 rx10 = make_float2(0.f, -sx), rx11 = make_float2(cx, 0.f);
            float2 ry00 = make_float2(cy, 0.f),  ry01 = make_float2(-sy, 0.f);
            float2 ry10 = make_float2(sy, 0.f),  ry11 = make_float2(cy, 0.f);
            float2 m00 = cadd(cmul(ry00, rx00), cmul(ry01, rx10));
            float2 m01 = cadd(cmul(ry00, rx01), cmul(ry01, rx11));
            float2 m10 = cadd(cmul(ry10, rx00), cmul(ry11, rx10));
            float2 m11 = cadd(cmul(ry10, rx01), cmul(ry11, rx11));
            float2 e0 = make_float2(cz, -sz), e1 = make_float2(cz, sz);
            Gs[t * 4 + 0] = cmul(e0, m00);
            Gs[t * 4 + 1] = cmul(e0, m01);
            Gs[t * 4 + 2] = cmul(e1, m10);
            Gs[t * 4 + 3] = cmul(e1, m11);
        }
        float ef[NL * (NQ - 1)];
        #pragma unroll
        for (int i = 0; i < NL * (NQ - 1); i++) ef[i] = ent[i];
        __syncthreads();

        float2 amp[16];
        #pragma unroll
        for (int r = 0; r < 16; r++)
            amp[r] = make_float2((lane * 16 + r == c) ? 1.f : 0.f, 0.f);

        #pragma unroll 1
        for (int li = 0; li < NL; li++) {
            const int l = NL - 1 - li;
            #pragma unroll
            for (int r = 0; r < 16; r++) {
                int idx = lane * 16 + r;
                float ang = 0.f;
                #pragma unroll
                for (int q = 0; q < NQ - 1; q++) {
                    int both = ((idx >> (9 - q)) & 1) & ((idx >> (8 - q)) & 1);
                    if (both) ang += ef[l * (NQ - 1) + q];
                }
                amp[r] = cmul(amp[r], make_float2(cosf(ang), sinf(ang)));
            }
            const float2* Gl = Gs + l * NQ * 4;
            #pragma unroll
            for (int qq = 0; qq < NQ; qq++) {
                const int q = 9 - qq;
                float2 u00 = Gl[q * 4 + 0], u10 = Gl[q * 4 + 1];   // transposed:
                float2 u01 = Gl[q * 4 + 2], u11 = Gl[q * 4 + 3];   // u01<->u10
                if (q >= 6) {
                    const int S = 1 << (9 - q);
                    #pragma unroll
                    for (int r = 0; r < 16; r++) {
                        if (r & S) continue;
                        float2 a = amp[r], b = amp[r + S];
                        float2 n0, n1;
                        n0.x = u00.x * a.x - u00.y * a.y + u01.x * b.x - u01.y * b.y;
                        n0.y = u00.x * a.y + u00.y * a.x + u01.x * b.y + u01.y * b.x;
                        n1.x = u10.x * a.x - u10.y * a.y + u11.x * b.x - u11.y * b.y;
                        n1.y = u10.x * a.y + u10.y * a.x + u11.x * b.y + u11.y * b.x;
                        amp[r] = n0; amp[r + S] = n1;
                    }
                } else {
                    const int mask = 32 >> q;
                    int bit = (lane >> (5 - q)) & 1;
                    float2 ua = bit ? u11 : u00;
                    float2 ub = bit ? u10 : u01;
                    #pragma unroll
                    for (int r = 0; r < 16; r++) {
                        float px = __shfl_xor(amp[r].x, mask, 64);
                        float py = __shfl_xor(amp[r].y, mask, 64);
                        float nx = ua.x * amp[r].x - ua.y * amp[r].y + ub.x * px - ub.y * py;
                        float ny = ua.x * amp[r].y + ua.y * amp[r].x + ub.x * py + ub.y * px;
                        amp[r] = make_float2(nx, ny);
                    }
                }
            }
        }

        // b2 fold at full fp32 precision (same row permutation as U)
        float accRe = 0.f, accIm = 0.f;
        #pragma unroll
        for (int i = 0; i < 4; i++) {
            float4 bv = *(const float4*)&bin[lane * 16 + i * 4];
            accRe += amp[i * 4 + 0].x * bv.x + amp[i * 4 + 1].x * bv.y
                   + amp[i * 4 + 2].x * bv.z + amp[i * 4 + 3].x * bv.w;
            accIm += amp[i * 4 + 0].y * bv.x + amp[i * 4 + 1].y * bv.y
                   + amp[i * 4 + 2].y * bv.z + amp[i * 4 + 3].y * bv.w;
        }
        #pragma unroll
        for (int m = 1; m < 64; m <<= 1) {
            accRe += __shfl_xor(accRe, m, 64);
            accIm += __shfl_xor(accIm, m, 64);
        }
        const int nR = ((c >> 5) << 6) + ((c & 1) << 5) + ((c >> 1) & 15);
        if (lane == 0) { b2[nR] = accRe; b2[nR + 16] = accIm; }

        u16x8 o0, o1, p0, p1;
        #pragma unroll
        for (int r = 0; r < 8; r++) {
            o0[r] = f2b(amp[r].x);     o1[r] = f2b(amp[r + 8].x);
            p0[r] = f2b(amp[r].y);     p1[r] = f2b(amp[r + 8].y);
        }
        unsigned short* rowRe = U + (size_t)nR * DIM + lane * 16;
        unsigned short* rowIm = U + (size_t)(nR + 16) * DIM + lane * 16;
        *(u16x8*)rowRe = o0; *(u16x8*)(rowRe + 8) = o1;
        *(u16x8*)rowIm = p0; *(u16x8*)(rowIm + 8) = p1;
        return;
    }

    if (bid < 768) {
        // ---------------- W_in transpose -> wtT ----------------
        __shared__ float tile[32][33];
        const int b2i = bid - 256;
        const int tx = t & 31, ty = t >> 5;   // 32x8
        const int d0 = (b2i & 15) * 32, j0 = (b2i >> 4) * 32;
        #pragma unroll
        for (int i = 0; i < 32; i += 8)
            tile[ty + i][tx] = W_in[(size_t)(j0 + ty + i) * DMODEL + d0 + tx];
        __syncthreads();
        #pragma unroll
        for (int i = 0; i < 32; i += 8)
            wtT[(size_t)(d0 + ty + i) * DIM + j0 + tx] = f2b(tile[tx][ty + i]);
        return;
    }

    // ---------------- x / W_out fp32 -> bf16 ----------------
    const int NX4 = TOKENS * DMODEL / 4;
    const int NW4 = DMODEL * DIM / 4;
    const int total = NX4 + NW4;
    const int stride = 2048 * 256;
    for (int i = (bid - 768) * 256 + t; i < total; i += stride) {
        const float* s; unsigned short* d; int j;
        if (i < NX4) { s = x;  d = xb;  j = i; }
        else         { s = w2; d = w2b; j = i - NX4; }
        float4 v = *(const float4*)&s[(size_t)j * 4];
        ushort4 o;
        o.x = f2b(v.x); o.y = f2b(v.y); o.z = f2b(v.z); o.w = f2b(v.w);
        *(ushort4*)&d[(size_t)j * 4] = o;
    }
}

// ---------------------------------------------------------------------------
// fold v2 (unchanged): 64x64 tiles, 256 blocks, BK=64, 32 KB dbuf.
// ---------------------------------------------------------------------------
__global__ __launch_bounds__(256)
void fold_kernel(const unsigned short* __restrict__ A, const unsigned short* __restrict__ B,
                 unsigned short* __restrict__ C) {
    __shared__ unsigned short sm[2 * 8192];
    const int t = threadIdx.x;
    const int wave = t >> 6, lane = t & 63;
    const int wm = wave >> 1, wn = wave & 1;
    const int laneR = lane & 15;
    const int bm0 = blockIdx.y * 64;
    const int bn0 = blockIdx.x * 64;

    const int csrc = (t & 7) ^ ((t >> 3) & 7);
    const int rowg = t >> 3;
    const unsigned aOff0 = (unsigned)(bm0 + rowg) * DIM + csrc * 8;
    const unsigned aOff1 = (unsigned)(bm0 + 32 + rowg) * DIM + csrc * 8;
    const unsigned bOff0 = (unsigned)(bn0 + rowg) * DIM + csrc * 8;
    const unsigned bOff1 = (unsigned)(bn0 + 32 + rowg) * DIM + csrc * 8;

    f32x4 acc[2][2] = {};

    #define F_STAGE(nbuf, kt) {                                            \
        unsigned short* d = sm + (nbuf) * 8192 + t * 8;                    \
        async_copy16(A + aOff0 + (kt) * 64, d);                            \
        async_copy16(A + aOff1 + (kt) * 64, d + 2048);                     \
        async_copy16(B + bOff0 + (kt) * 64, d + 4096);                     \
        async_copy16(B + bOff1 + (kt) * 64, d + 6144);                     \
    }

    F_STAGE(0, 0);
    asm volatile("s_waitcnt vmcnt(0)" ::: "memory");
    __syncthreads();

    #pragma unroll
    for (int kt = 0; kt < 16; kt++) {
        const int cur = kt & 1;
        if (kt < 15) F_STAGE(cur ^ 1, kt + 1);
        const unsigned short* la = sm + cur * 8192;
        const unsigned short* lb = la + 4096;
        #pragma unroll
        for (int kk = 0; kk < 2; kk++) {
            bf16x8 af[2], bfr[2];
            #pragma unroll
            for (int i = 0; i < 2; i++) {
                int row = wm * 32 + i * 16 + laneR;
                int slot = ((lane >> 4) + kk * 4) ^ (row & 7);
                af[i] = *(const bf16x8*)&la[row * 64 + slot * 8];
                int nrow = wn * 32 + i * 16 + laneR;
                int nslot = ((lane >> 4) + kk * 4) ^ (nrow & 7);
                bfr[i] = *(const bf16x8*)&lb[nrow * 64 + nslot * 8];
            }
            #pragma unroll
            for (int i = 0; i < 2; i++)
                #pragma unroll
                for (int j = 0; j < 2; j++)
                    acc[i][j] = __builtin_amdgcn_mfma_f32_16x16x32_bf16(af[i], bfr[j], acc[i][j], 0, 0, 0);
        }
        asm volatile("s_waitcnt vmcnt(0)" ::: "memory");
        __syncthreads();
    }
    #undef F_STAGE

    #pragma unroll
    for (int i = 0; i < 2; i++)
        #pragma unroll
        for (int j = 0; j < 2; j++) {
            int col = bn0 + wn * 32 + j * 16 + laneR;
            #pragma unroll
            for (int r = 0; r < 4; r++) {
                int row = bm0 + wm * 32 + i * 16 + (lane >> 4) * 4 + r;
                C[(size_t)row * DMODEL + col] = f2b(acc[i][j][r]);
            }
        }
}

// ---------------------------------------------------------------------------
// gemm1 v7: K-loop identical to v6 (measured-best). Epilogue v2: with the
// v2 U-row mapping, each lane's j=0..3 y-cols are (Re,Im,Re,Im) of two
// MEMORY-ADJACENT p-cols -> 32 ushort2 stores/thread (was 64 x 2B), 64B
// contiguous per 16-lane group.
// ---------------------------------------------------------------------------
__global__ __launch_bounds__(512, 2)
void gemm1_kernel(const unsigned short* __restrict__ A, const unsigned short* __restrict__ B,
                  const float* __restrict__ bias, unsigned short* __restrict__ P) {
    const int K = DMODEL;                       // 512
    __shared__ unsigned short sm[2 * 32768];    // 128 KB
    const int t = threadIdx.x;
    const int wave = t >> 6, lane = t & 63;
    const int wm = wave >> 2, wn = wave & 3;    // 2 x 4 waves
    const int laneR = lane & 15;

    const int bid = blockIdx.x;                 // 512 blocks
    const int swz = (bid & 7) * 64 + (bid >> 3);
    const int bm0 = (swz >> 3) * 256;
    const int bn0 = (swz & 7) * 256;

    const int csrc = (t & 3) ^ ((t >> 3) & 3);
    const int rowg = t >> 2;
    const unsigned aOff0 = (unsigned)(bm0 + rowg) * DMODEL + csrc * 8;
    const unsigned aOff1 = (unsigned)(bm0 + 128 + rowg) * DMODEL + csrc * 8;
    const unsigned bOff0 = (unsigned)(bn0 + rowg) * DMODEL + csrc * 8;
    const unsigned bOff1 = (unsigned)(bn0 + 128 + rowg) * DMODEL + csrc * 8;

    const int slotc = (((lane >> 4) ^ ((lane >> 1) & 3)) & 3) * 8;

    f32x4 acc[8][4] = {};

    #define G1_STAGE(nbuf, kk, kb)                                                 \
    {                                                                              \
        unsigned short* d0 = sm + (nbuf) * 32768 + (kk) * 8192 + wave * 512;       \
        async_copy16(A + aOff0 + (kb) + (kk) * 32, d0);                            \
        async_copy16(A + aOff1 + (kb) + (kk) * 32, d0 + 4096);                     \
        async_copy16(B + bOff0 + (kb) + (kk) * 32, d0 + 16384);                    \
        async_copy16(B + bOff1 + (kb) + (kk) * 32, d0 + 20480);                    \
    }

    #define G1_COMPUTE(cbuf, kk)                                                   \
    {                                                                              \
        const unsigned short* la = sm + (cbuf) * 32768 + (kk) * 8192;              \
        const unsigned short* lb = la + 16384;                                     \
        bf16x8 af[8], bfr[4];                                                      \
        _Pragma("unroll")                                                          \
        for (int i = 0; i < 8; i++)                                                \
            af[i] = *(const bf16x8*)&la[(wm * 128 + i * 16 + laneR) * 32 + slotc]; \
        _Pragma("unroll")                                                          \
        for (int j = 0; j < 4; j++)                                                \
            bfr[j] = *(const bf16x8*)&lb[(wn * 64 + j * 16 + laneR) * 32 + slotc]; \
        __builtin_amdgcn_s_setprio(1);                                             \
        _Pragma("unroll")                                                          \
        for (int i = 0; i < 8; i++)                                                \
            _Pragma("unroll")                                                      \
            for (int j = 0; j < 4; j++)                                            \
                acc[i][j] = __builtin_amdgcn_mfma_f32_16x16x32_bf16(af[i], bfr[j], acc[i][j], 0, 0, 0); \
        __builtin_amdgcn_s_setprio(0);                                             \
    }

    G1_STAGE(0, 0, 0);
    G1_STAGE(0, 1, 0);
    asm volatile("s_waitcnt vmcnt(4)" ::: "memory");
    asm volatile("s_barrier" ::: "memory");

    #pragma unroll
    for (int kt = 0; kt < 7; kt++) {
        const int cur = kt & 1, nxt = cur ^ 1;
        const unsigned kb = (unsigned)(kt + 1) * 64;
        G1_STAGE(nxt, 0, kb);
        G1_COMPUTE(cur, 0);
        asm volatile("s_waitcnt vmcnt(4)" ::: "memory");
        asm volatile("s_barrier" ::: "memory");
        G1_STAGE(nxt, 1, kb);
        G1_COMPUTE(cur, 1);
        asm volatile("s_waitcnt vmcnt(4)" ::: "memory");
        asm volatile("s_barrier" ::: "memory");
    }
    G1_COMPUTE(1, 0);
    asm volatile("s_waitcnt vmcnt(0)" ::: "memory");
    asm volatile("s_barrier" ::: "memory");
    G1_COMPUTE(1, 1);

    #undef G1_STAGE
    #undef G1_COMPUTE

    // epilogue v2: per-lane |y|^2 for two adjacent p-cols, ushort2 stores
    const int cb0 = bn0 + wn * 64 + laneR;
    const float b0 = bias[cb0];
    const float b1 = bias[cb0 + 16];
    const float b2v = bias[cb0 + 32];
    const float b3 = bias[cb0 + 48];
    const int pc2 = (bn0 >> 1) + wn * 32 + laneR * 2;
    #pragma unroll
    for (int i = 0; i < 8; i++) {
        #pragma unroll
        for (int r = 0; r < 4; r++) {
            int row = bm0 + wm * 128 + i * 16 + (lane >> 4) * 4 + r;
            float v0 = acc[i][0][r] + b0, v1 = acc[i][1][r] + b1;
            float v2 = acc[i][2][r] + b2v, v3 = acc[i][3][r] + b3;
            ushort2 o;
            o.x = f2b(v0 * v0 + v1 * v1);
            o.y = f2b(v2 * v2 + v3 * v3);
            *(ushort2*)&P[(size_t)row * DIM + pc2] = o;
        }
    }
}

// ---------------------------------------------------------------------------
// gemm2_ln v3: same K-pipeline as v2 (measured-best slack depth). Change:
// n2 ones-MFMA duty distributed across wn waves per K-tile (wn == n&3) —
// removes the wn==0 per-phase straggler; partial accN reduced via LDS.
// ---------------------------------------------------------------------------
__global__ __launch_bounds__(512)
void gemm2_ln_kernel(const unsigned short* __restrict__ A,   // p [TOKENS][DIM]
                     const unsigned short* __restrict__ B,   // w2b [DMODEL][DIM]
                     const float* __restrict__ bias,
                     const float* __restrict__ lw, const float* __restrict__ lb,
                     float* __restrict__ out) {
    __shared__ unsigned short sm[2 * 36864];                 // 144 KB
    __shared__ float redS[4][64], redQ[4][64];
    __shared__ float muS[64], rsS[64], n2s[64], n2p[4][64];
    const int t = threadIdx.x, wave = t >> 6, lane = t & 63;
    const int wm = wave >> 2, wn = wave & 3;
    const int laneR = lane & 15;
    const int bm0 = blockIdx.x * 64;

    const int csrc = (t & 3) ^ ((t >> 3) & 3);
    const int akk  = t >> 8, arow = (t >> 2) & 63;
    const unsigned aSrc = (unsigned)(bm0 + arow) * DIM + akk * 32 + csrc * 8;
    const int brow = t >> 2;
    const int slotc = (((lane >> 4) ^ ((lane >> 1) & 3)) & 3) * 8;

    f32x4 acc[2][8] = {};
    f32x4 accN[2] = {};
    bf16x8 ones;
    #pragma unroll
    for (int r = 0; r < 8; r++) ones[r] = (__bf16)1.0f;

    #define G2_STAGE_A(nbuf, kb) {                                          \
        async_copy16(A + aSrc + (kb), sm + (nbuf) * 36864 + t * 8);         \
    }
    #define G2_STAGE_B(nbuf, kk, kb) {                                      \
        unsigned short* d = sm + (nbuf) * 36864 + 4096 + (kk) * 16384 + t * 8; \
        const unsigned short* s0 = B + (size_t)brow * DIM + (kb) + (kk) * 32 + csrc * 8; \
        async_copy16(s0,                 d);                                 \
        async_copy16(s0 + 128 * DIM,     d + 4096);                         \
        async_copy16(s0 + 256 * DIM,     d + 8192);                         \
        async_copy16(s0 + 384 * DIM,     d + 12288);                        \
    }
    #define G2_COMPUTE(cbuf, kk, sel) {                                     \
        const unsigned short* la  = sm + (cbuf) * 36864 + (kk) * 2048;      \
        const unsigned short* lbp = sm + (cbuf) * 36864 + 4096 + (kk) * 16384; \
        bf16x8 af[2], bfr[8];                                               \
        _Pragma("unroll")                                                   \
        for (int i = 0; i < 2; i++)                                         \
            af[i] = *(const bf16x8*)&la[(wm * 32 + i * 16 + laneR) * 32 + slotc]; \
        _Pragma("unroll")                                                   \
        for (int j = 0; j < 8; j++)                                         \
            bfr[j] = *(const bf16x8*)&lbp[(wn * 128 + j * 16 + laneR) * 32 + slotc]; \
        __builtin_amdgcn_s_setprio(1);                                      \
        _Pragma("unroll")                                                   \
        for (int i = 0; i < 2; i++)                                         \
            _Pragma("unroll")                                               \
            for (int j = 0; j < 8; j++)                                     \
                acc[i][j] = __builtin_amdgcn_mfma_f32_16x16x32_bf16(af[i], bfr[j], acc[i][j], 0, 0, 0); \
        if (wn == (sel)) {                                                  \
            _Pragma("unroll")                                               \
            for (int i = 0; i < 2; i++)                                     \
                accN[i] = __builtin_amdgcn_mfma_f32_16x16x32_bf16(af[i], ones, accN[i], 0, 0, 0); \
        }                                                                   \
        __builtin_amdgcn_s_setprio(0);                                      \
    }

    G2_STAGE_A(0, 0); G2_STAGE_B(0, 0, 0); G2_STAGE_B(0, 1, 0);
    asm volatile("s_waitcnt vmcnt(4)" ::: "memory");
    asm volatile("s_barrier" ::: "memory");

    #pragma unroll
    for (int n = 0; n < 15; n++) {
        const int cb = n & 1, nb = cb ^ 1;
        const unsigned kb = (unsigned)(n + 1) * 64;
        G2_STAGE_A(nb, kb); G2_STAGE_B(nb, 0, kb);
        G2_COMPUTE(cb, 0, n & 3);
        asm volatile("s_waitcnt vmcnt(5)" ::: "memory");
        asm volatile("s_barrier" ::: "memory");
        G2_STAGE_B(nb, 1, kb);
        G2_COMPUTE(cb, 1, n & 3);
        asm volatile("s_waitcnt vmcnt(4)" ::: "memory");
        asm volatile("s_barrier" ::: "memory");
    }
    G2_COMPUTE(1, 0, 3);
    asm volatile("s_waitcnt vmcnt(0)" ::: "memory");
    asm volatile("s_barrier" ::: "memory");
    G2_COMPUTE(1, 1, 3);

    #undef G2_STAGE_A
    #undef G2_STAGE_B
    #undef G2_COMPUTE

    // ---- LN epilogue over 64 rows ----
    if (laneR == 0) {
        #pragma unroll
        for (int i = 0; i < 2; i++)
            #pragma unroll
            for (int r = 0; r < 4; r++)
                n2p[wn][wm * 32 + i * 16 + (lane >> 4) * 4 + r] = accN[i][r];
    }
    __syncthreads();
    if (t < 64)
        n2s[t] = n2p[0][t] + n2p[1][t] + n2p[2][t] + n2p[3][t];
    __syncthreads();

    float bvj[8];
    #pragma unroll
    for (int j = 0; j < 8; j++) bvj[j] = bias[wn * 128 + j * 16 + laneR];

    #pragma unroll
    for (int i = 0; i < 2; i++)
        #pragma unroll
        for (int r = 0; r < 4; r++) {
            int rl = wm * 32 + i * 16 + (lane >> 4) * 4 + r;
            float nn = 1.0f / fmaxf(n2s[rl], 1e-24f);
            float s = 0.f, q = 0.f;
            #pragma unroll
            for (int j = 0; j < 8; j++) {
                float val = acc[i][j][r] * nn + bvj[j];
                acc[i][j][r] = val;
                s += val; q += val * val;
            }
            s += __shfl_xor(s, 1, 64); q += __shfl_xor(q, 1, 64);
            s += __shfl_xor(s, 2, 64); q += __shfl_xor(q, 2, 64);
            s += __shfl_xor(s, 4, 64); q += __shfl_xor(q, 4, 64);
            s += __shfl_xor(s, 8, 64); q += __shfl_xor(q, 8, 64);
            if (laneR == 0) { redS[wn][rl] = s; redQ[wn][rl] = q; }
        }
    __syncthreads();
    if (t < 64) {
        float s = redS[0][t] + redS[1][t] + redS[2][t] + redS[3][t];
        float q = redQ[0][t] + redQ[1][t] + redQ[2][t] + redQ[3][t];
        float mu = s * (1.0f / DMODEL);
        float var = q * (1.0f / DMODEL) - mu * mu;
        muS[t] = mu;
        rsS[t] = rsqrtf(var + 1e-5f);
    }
    __syncthreads();
    #pragma unroll
    for (int i = 0; i < 2; i++)
        #pragma unroll
        for (int j = 0; j < 8; j++) {
            int col = wn * 128 + j * 16 + laneR;
            float w = lw[col], bb = lb[col];
            #pragma unroll
            for (int r = 0; r < 4; r++) {
                int rl = wm * 32 + i * 16 + (lane >> 4) * 4 + r;
                out[(size_t)(bm0 + rl) * DMODEL + col] =
                    (acc[i][j][r] - muS[rl]) * rsS[rl] * w + bb;
            }
        }
}

extern "C" void kernel_launch(void* const* d_in, const int* in_sizes, int n_in,
                              void* d_out, int out_size, void* d_ws, size_t ws_size,
                              hipStream_t stream) {
    (void)in_sizes; (void)n_in; (void)out_size; (void)ws_size;
    const float* x     = (const float*)d_in[0];
    const float* W_in  = (const float*)d_in[1];
    const float* b_in  = (const float*)d_in[2];
    const float* W_out = (const float*)d_in[3];
    const float* b_out = (const float*)d_in[4];
    const float* rot   = (const float*)d_in[5];
    const float* ent   = (const float*)d_in[6];
    const float* ln_w  = (const float*)d_in[7];
    const float* ln_b  = (const float*)d_in[8];
    float* out = (float*)d_out;

    char* ws = (char*)d_ws;
    unsigned short* p    = (unsigned short*)ws;                     // [16384][1024] 32 MB
    unsigned short* x_bf = (unsigned short*)(ws + 33554432ull);     // 16 MB
    unsigned short* wtT  = (unsigned short*)(ws + 50331648ull);     // [512][1024] 1 MB
    unsigned short* w2b  = (unsigned short*)(ws + 51380224ull);     // [512][1024] 1 MB
    unsigned short* Ucat = (unsigned short*)(ws + 52428800ull);     // [2048][1024] 4 MB
    unsigned short* W1c  = (unsigned short*)(ws + 56623104ull);     // [2048][512] 2 MB
    float*          b2   = (float*)(ws + 58720256ull);              // [2048] 8 KB
    // high-water ~56 MB

    prep_all_kernel<<<2816, 256, 0, stream>>>(x, x_bf, W_out, w2b, W_in, wtT,
                                              rot, ent, b_in, Ucat, b2);
    fold_kernel<<<dim3(DMODEL / 64, 2 * DIM / 64), 256, 0, stream>>>(Ucat, wtT, W1c);
    gemm1_kernel<<<512, 512, 0, stream>>>(x_bf, W1c, b2, p);
    gemm2_ln_kernel<<<TOKENS / 64, 512, 0, stream>>>(
        p, w2b, b_out, ln_w, ln_b, out);
}

// Round 8
// 195.374 us; speedup vs baseline: 1.0070x; 1.0070x over previous
//
#include <hip/hip_runtime.h>
#include <cstdint>

#define TOKENS 16384
#define DMODEL 512
#define DIM    1024
#define NQ     10
#define NL     2

typedef __bf16 bf16x8 __attribute__((ext_vector_type(8)));
typedef float  f32x4  __attribute__((ext_vector_type(4)));
typedef unsigned short u16x8 __attribute__((ext_vector_type(8)));

__device__ __forceinline__ float b2f(unsigned short h) {
    union { unsigned u; float f; } v; v.u = ((unsigned)h) << 16; return v.f;
}
__device__ __forceinline__ unsigned short f2b(float f) {
    unsigned u = __builtin_bit_cast(unsigned, f);
    return (unsigned short)((u + 0x7FFFu + ((u >> 16) & 1u)) >> 16);  // RNE
}
__device__ __forceinline__ float2 cmul(float2 a, float2 b) {
    return make_float2(a.x * b.x - a.y * b.y, a.x * b.y + a.y * b.x);
}
__device__ __forceinline__ float2 cadd(float2 a, float2 b) {
    return make_float2(a.x + b.x, a.y + b.y);
}
__device__ __forceinline__ void async_copy16(const void* g, void* l) {
    __builtin_amdgcn_global_load_lds((const __attribute__((address_space(1))) void*)g,
                                     (__attribute__((address_space(3))) void*)l, 16, 0, 0);
}

// ---------------------------------------------------------------------------
// prep_all: block-id branched fused prep.  (unchanged; v2 U-row mapping)
// ---------------------------------------------------------------------------
__global__ __launch_bounds__(256)
void prep_all_kernel(const float* __restrict__ x,  unsigned short* __restrict__ xb,
                     const float* __restrict__ w2, unsigned short* __restrict__ w2b,
                     const float* __restrict__ W_in, unsigned short* __restrict__ wtT,
                     const float* __restrict__ rot, const float* __restrict__ ent,
                     const float* __restrict__ bin,
                     unsigned short* __restrict__ U, float* __restrict__ b2) {
    const int bid = blockIdx.x;
    const int t = threadIdx.x;

    if (bid < 256) {
        // ---------------- buildU + b2 ----------------
        __shared__ float2 Gs[NL * NQ * 4];
        const int lane = t & 63;
        const int c = bid * 4 + (t >> 6);

        if (t < NL * NQ) {
            float tx = rot[t * 3 + 0] * 0.5f;
            float ty = rot[t * 3 + 1] * 0.5f;
            float tz = rot[t * 3 + 2] * 0.5f;
            float cx = cosf(tx), sx = sinf(tx);
            float cy = cosf(ty), sy = sinf(ty);
            float cz = cosf(tz), sz = sinf(tz);
            float2 rx00 = make_float2(cx, 0.f),  rx01 = make_float2(0.f, -sx);
            float2 rx10 = make_float2(0.f, -sx), rx11 = make_float2(cx, 0.f);
            float2 ry00 = make_float2(cy, 0.f),  ry01 = make_float2(-sy, 0.f);
            float2 ry10 = make_float2(sy, 0.f),  ry11 = make_float2(cy, 0.f);
            float2 m00 = cadd(cmul(ry00, rx00), cmul(ry01, rx10));
            float2 m01 = cadd(cmul(ry00, rx01), cmul(ry01, rx11));
            float2 m10 = cadd(cmul(ry10, rx00), cmul(ry11, rx10));
            float2 m11 = cadd(cmul(ry10, rx01), cmul(ry11, rx11));
            float2 e0 = make_float2(cz, -sz), e1 = make_float2(cz, sz);
            Gs[t * 4 + 0] = cmul(e0, m00);
            Gs[t * 4 + 1] = cmul(e0, m01);
            Gs[t * 4 + 2] = cmul(e1, m10);
            Gs[t * 4 + 3] = cmul(e1, m11);
        }
        float ef[NL * (NQ - 1)];
        #pragma unroll
        for (int i = 0; i < NL * (NQ - 1); i++) ef[i] = ent[i];
        __syncthreads();

        float2 amp[16];
        #pragma unroll
        for (int r = 0; r < 16; r++)
            amp[r] = make_float2((lane * 16 + r == c) ? 1.f : 0.f, 0.f);

        #pragma unroll 1
        for (int li = 0; li < NL; li++) {
            const int l = NL - 1 - li;
            #pragma unroll
            for (int r = 0; r < 16; r++) {
                int idx = lane * 16 + r;
                float ang = 0.f;
                #pragma unroll
                for (int q = 0; q < NQ - 1; q++) {
                    int both = ((idx >> (9 - q)) & 1) & ((idx >> (8 - q)) & 1);
                    if (both) ang += ef[l * (NQ - 1) + q];
                }
                amp[r] = cmul(amp[r], make_float2(cosf(ang), sinf(ang)));
            }
            const float2* Gl = Gs + l * NQ * 4;
            #pragma unroll
            for (int qq = 0; qq < NQ; qq++) {
                const int q = 9 - qq;
                float2 u00 = Gl[q * 4 + 0], u10 = Gl[q * 4 + 1];   // transposed:
                float2 u01 = Gl[q * 4 + 2], u11 = Gl[q * 4 + 3];   // u01<->u10
                if (q >= 6) {
                    const int S = 1 << (9 - q);
                    #pragma unroll
                    for (int r = 0; r < 16; r++) {
                        if (r & S) continue;
                        float2 a = amp[r], b = amp[r + S];
                        float2 n0, n1;
                        n0.x = u00.x * a.x - u00.y * a.y + u01.x * b.x - u01.y * b.y;
                        n0.y = u00.x * a.y + u00.y * a.x + u01.x * b.y + u01.y * b.x;
                        n1.x = u10.x * a.x - u10.y * a.y + u11.x * b.x - u11.y * b.y;
                        n1.y = u10.x * a.y + u10.y * a.x + u11.x * b.y + u11.y * b.x;
                        amp[r] = n0; amp[r + S] = n1;
                    }
                } else {
                    const int mask = 32 >> q;
                    int bit = (lane >> (5 - q)) & 1;
                    float2 ua = bit ? u11 : u00;
                    float2 ub = bit ? u10 : u01;
                    #pragma unroll
                    for (int r = 0; r < 16; r++) {
                        float px = __shfl_xor(amp[r].x, mask, 64);
                        float py = __shfl_xor(amp[r].y, mask, 64);
                        float nx = ua.x * amp[r].x - ua.y * amp[r].y + ub.x * px - ub.y * py;
                        float ny = ua.x * amp[r].y + ua.y * amp[r].x + ub.x * py + ub.y * px;
                        amp[r] = make_float2(nx, ny);
                    }
                }
            }
        }

        // b2 fold at full fp32 precision (same row permutation as U)
        float accRe = 0.f, accIm = 0.f;
        #pragma unroll
        for (int i = 0; i < 4; i++) {
            float4 bv = *(const float4*)&bin[lane * 16 + i * 4];
            accRe += amp[i * 4 + 0].x * bv.x + amp[i * 4 + 1].x * bv.y
                   + amp[i * 4 + 2].x * bv.z + amp[i * 4 + 3].x * bv.w;
            accIm += amp[i * 4 + 0].y * bv.x + amp[i * 4 + 1].y * bv.y
                   + amp[i * 4 + 2].y * bv.z + amp[i * 4 + 3].y * bv.w;
        }
        #pragma unroll
        for (int m = 1; m < 64; m <<= 1) {
            accRe += __shfl_xor(accRe, m, 64);
            accIm += __shfl_xor(accIm, m, 64);
        }
        const int nR = ((c >> 5) << 6) + ((c & 1) << 5) + ((c >> 1) & 15);
        if (lane == 0) { b2[nR] = accRe; b2[nR + 16] = accIm; }

        u16x8 o0, o1, p0, p1;
        #pragma unroll
        for (int r = 0; r < 8; r++) {
            o0[r] = f2b(amp[r].x);     o1[r] = f2b(amp[r + 8].x);
            p0[r] = f2b(amp[r].y);     p1[r] = f2b(amp[r + 8].y);
        }
        unsigned short* rowRe = U + (size_t)nR * DIM + lane * 16;
        unsigned short* rowIm = U + (size_t)(nR + 16) * DIM + lane * 16;
        *(u16x8*)rowRe = o0; *(u16x8*)(rowRe + 8) = o1;
        *(u16x8*)rowIm = p0; *(u16x8*)(rowIm + 8) = p1;
        return;
    }

    if (bid < 768) {
        // ---------------- W_in transpose -> wtT ----------------
        __shared__ float tile[32][33];
        const int b2i = bid - 256;
        const int tx = t & 31, ty = t >> 5;   // 32x8
        const int d0 = (b2i & 15) * 32, j0 = (b2i >> 4) * 32;
        #pragma unroll
        for (int i = 0; i < 32; i += 8)
            tile[ty + i][tx] = W_in[(size_t)(j0 + ty + i) * DMODEL + d0 + tx];
        __syncthreads();
        #pragma unroll
        for (int i = 0; i < 32; i += 8)
            wtT[(size_t)(d0 + ty + i) * DIM + j0 + tx] = f2b(tile[tx][ty + i]);
        return;
    }

    // ---------------- x / W_out fp32 -> bf16 ----------------
    const int NX4 = TOKENS * DMODEL / 4;
    const int NW4 = DMODEL * DIM / 4;
    const int total = NX4 + NW4;
    const int stride = 2048 * 256;
    for (int i = (bid - 768) * 256 + t; i < total; i += stride) {
        const float* s; unsigned short* d; int j;
        if (i < NX4) { s = x;  d = xb;  j = i; }
        else         { s = w2; d = w2b; j = i - NX4; }
        float4 v = *(const float4*)&s[(size_t)j * 4];
        ushort4 o;
        o.x = f2b(v.x); o.y = f2b(v.y); o.z = f2b(v.z); o.w = f2b(v.w);
        *(ushort4*)&d[(size_t)j * 4] = o;
    }
}

// ---------------------------------------------------------------------------
// fold v2 (unchanged): 64x64 tiles, 256 blocks, BK=64, 32 KB dbuf.
// ---------------------------------------------------------------------------
__global__ __launch_bounds__(256)
void fold_kernel(const unsigned short* __restrict__ A, const unsigned short* __restrict__ B,
                 unsigned short* __restrict__ C) {
    __shared__ unsigned short sm[2 * 8192];
    const int t = threadIdx.x;
    const int wave = t >> 6, lane = t & 63;
    const int wm = wave >> 1, wn = wave & 1;
    const int laneR = lane & 15;
    const int bm0 = blockIdx.y * 64;
    const int bn0 = blockIdx.x * 64;

    const int csrc = (t & 7) ^ ((t >> 3) & 7);
    const int rowg = t >> 3;
    const unsigned aOff0 = (unsigned)(bm0 + rowg) * DIM + csrc * 8;
    const unsigned aOff1 = (unsigned)(bm0 + 32 + rowg) * DIM + csrc * 8;
    const unsigned bOff0 = (unsigned)(bn0 + rowg) * DIM + csrc * 8;
    const unsigned bOff1 = (unsigned)(bn0 + 32 + rowg) * DIM + csrc * 8;

    f32x4 acc[2][2] = {};

    #define F_STAGE(nbuf, kt) {                                            \
        unsigned short* d = sm + (nbuf) * 8192 + t * 8;                    \
        async_copy16(A + aOff0 + (kt) * 64, d);                            \
        async_copy16(A + aOff1 + (kt) * 64, d + 2048);                     \
        async_copy16(B + bOff0 + (kt) * 64, d + 4096);                     \
        async_copy16(B + bOff1 + (kt) * 64, d + 6144);                     \
    }

    F_STAGE(0, 0);
    asm volatile("s_waitcnt vmcnt(0)" ::: "memory");
    __syncthreads();

    #pragma unroll
    for (int kt = 0; kt < 16; kt++) {
        const int cur = kt & 1;
        if (kt < 15) F_STAGE(cur ^ 1, kt + 1);
        const unsigned short* la = sm + cur * 8192;
        const unsigned short* lb = la + 4096;
        #pragma unroll
        for (int kk = 0; kk < 2; kk++) {
            bf16x8 af[2], bfr[2];
            #pragma unroll
            for (int i = 0; i < 2; i++) {
                int row = wm * 32 + i * 16 + laneR;
                int slot = ((lane >> 4) + kk * 4) ^ (row & 7);
                af[i] = *(const bf16x8*)&la[row * 64 + slot * 8];
                int nrow = wn * 32 + i * 16 + laneR;
                int nslot = ((lane >> 4) + kk * 4) ^ (nrow & 7);
                bfr[i] = *(const bf16x8*)&lb[nrow * 64 + nslot * 8];
            }
            #pragma unroll
            for (int i = 0; i < 2; i++)
                #pragma unroll
                for (int j = 0; j < 2; j++)
                    acc[i][j] = __builtin_amdgcn_mfma_f32_16x16x32_bf16(af[i], bfr[j], acc[i][j], 0, 0, 0);
        }
        asm volatile("s_waitcnt vmcnt(0)" ::: "memory");
        __syncthreads();
    }
    #undef F_STAGE

    #pragma unroll
    for (int i = 0; i < 2; i++)
        #pragma unroll
        for (int j = 0; j < 2; j++) {
            int col = bn0 + wn * 32 + j * 16 + laneR;
            #pragma unroll
            for (int r = 0; r < 4; r++) {
                int row = bm0 + wm * 32 + i * 16 + (lane >> 4) * 4 + r;
                C[(size_t)row * DMODEL + col] = f2b(acc[i][j][r]);
            }
        }
}

// ---------------------------------------------------------------------------
// gemm1 v9: occupancy experiment, REGISTER-FEASIBLE this time.
// 256M x 128N tile, 8 waves (2Mx4N) -> per-wave 128x32, acc = 64 VGPR
// (total ~115 < 128 cap). BK=32 dbuf = 48 KB LDS. launch_bounds(512,4)
// -> 2 blocks/CU (16 waves/CU, double v6): co-resident block covers the
// per-tile vmcnt(0) drain (fold-proven TLP).
// Grid 1024, XCD-bijective swizzle: 8 M-tiles x 16 N-tiles per XCD.
// Epilogue: wave's j=0/j=1 cols are Re/Im partners under the v2 U-mapping
// (col b*32+q <-> +16, p-col = q*2+b); per-lane |y|^2, 2B stores.
// ---------------------------------------------------------------------------
__global__ __launch_bounds__(512, 4)
void gemm1_kernel(const unsigned short* __restrict__ A, const unsigned short* __restrict__ B,
                  const float* __restrict__ bias, unsigned short* __restrict__ P) {
    // elems: buf*12288 + { A: row*32 + slot*8 (256 rows) ;
    //                      B: 8192 + row*32 + slot*8 (128 rows) }   (48 KB)
    __shared__ unsigned short sm[2 * 12288];
    const int t = threadIdx.x;
    const int wave = t >> 6, lane = t & 63;
    const int wm = wave >> 2, wn = wave & 3;    // 2M x 4N
    const int laneR = lane & 15;

    const int bid = blockIdx.x;                 // 1024 blocks
    const int swz = (bid & 7) * 128 + (bid >> 3);
    const int bm0 = (swz >> 4) * 256;           // 64 M-tiles
    const int bn0 = (swz & 15) * 128;           // 16 N-tiles

    // staging: A chunks c=t (rows 0-127) and c=t+512 (rows 128-255); B c=t.
    // row = c>>2, lin slot = c&3, src slot = (c&3)^((row>>1)&3) = (t&3)^((t>>3)&3)
    const int csrc = (t & 3) ^ ((t >> 3) & 3);
    const int rowg = t >> 2;                    // 0..127
    const unsigned aOff0 = (unsigned)(bm0 + rowg) * DMODEL + csrc * 8;
    const unsigned aOff1 = (unsigned)(bm0 + 128 + rowg) * DMODEL + csrc * 8;
    const unsigned bOff0 = (unsigned)(bn0 + rowg) * DMODEL + csrc * 8;

    const int slotc = (((lane >> 4) ^ ((lane >> 1) & 3)) & 3) * 8;

    f32x4 acc[8][2] = {};

    #define G1_STAGE(nbuf, kb)                                                     \
    {                                                                              \
        unsigned short* d0 = sm + (nbuf) * 12288 + wave * 512;                     \
        async_copy16(A + aOff0 + (kb), d0);                                        \
        async_copy16(A + aOff1 + (kb), d0 + 4096);                                 \
        async_copy16(B + bOff0 + (kb), d0 + 8192);                                 \
    }

    #define G1_COMPUTE(cbuf)                                                       \
    {                                                                              \
        const unsigned short* la = sm + (cbuf) * 12288;                            \
        const unsigned short* lb = la + 8192;                                      \
        bf16x8 af[8], bfr[2];                                                      \
        _Pragma("unroll")                                                          \
        for (int i = 0; i < 8; i++)                                                \
            af[i] = *(const bf16x8*)&la[(wm * 128 + i * 16 + laneR) * 32 + slotc]; \
        _Pragma("unroll")                                                          \
        for (int j = 0; j < 2; j++)                                                \
            bfr[j] = *(const bf16x8*)&lb[(wn * 32 + j * 16 + laneR) * 32 + slotc]; \
        __builtin_amdgcn_s_setprio(1);                                             \
        _Pragma("unroll")                                                          \
        for (int i = 0; i < 8; i++)                                                \
            _Pragma("unroll")                                                      \
            for (int j = 0; j < 2; j++)                                            \
                acc[i][j] = __builtin_amdgcn_mfma_f32_16x16x32_bf16(af[i], bfr[j], acc[i][j], 0, 0, 0); \
        __builtin_amdgcn_s_setprio(0);                                             \
    }

    G1_STAGE(0, 0);
    asm volatile("s_waitcnt vmcnt(0)" ::: "memory");
    asm volatile("s_barrier" ::: "memory");

    #pragma unroll
    for (int kt = 0; kt < 16; kt++) {
        const int cur = kt & 1;
        if (kt < 15) G1_STAGE(cur ^ 1, (unsigned)(kt + 1) * 32);
        G1_COMPUTE(cur);
        asm volatile("s_waitcnt vmcnt(0)" ::: "memory");
        asm volatile("s_barrier" ::: "memory");
    }

    #undef G1_STAGE
    #undef G1_COMPUTE

    // epilogue: per-lane |y|^2 (j=0 Re, j=1 Im partner), 2B stores
    const int g64 = wn >> 1, bsel = wn & 1;
    const int colRe = bn0 + g64 * 64 + bsel * 32 + laneR;
    const float bRe = bias[colRe];
    const float bIm = bias[colRe + 16];
    const int pc = (bn0 >> 1) + g64 * 32 + laneR * 2 + bsel;
    #pragma unroll
    for (int i = 0; i < 8; i++) {
        #pragma unroll
        for (int r = 0; r < 4; r++) {
            int row = bm0 + wm * 128 + i * 16 + (lane >> 4) * 4 + r;
            float vr = acc[i][0][r] + bRe;
            float vi = acc[i][1][r] + bIm;
            P[(size_t)row * DIM + pc] = f2b(vr * vr + vi * vi);
        }
    }
}

// ---------------------------------------------------------------------------
// gemm2_ln v3 (unchanged): BM=64 x BN=512, BK=64, 2-phase counted-vmcnt,
// distributed ones-MFMA duty, fused n2-normalize + LayerNorm.
// ---------------------------------------------------------------------------
__global__ __launch_bounds__(512)
void gemm2_ln_kernel(const unsigned short* __restrict__ A,   // p [TOKENS][DIM]
                     const unsigned short* __restrict__ B,   // w2b [DMODEL][DIM]
                     const float* __restrict__ bias,
                     const float* __restrict__ lw, const float* __restrict__ lb,
                     float* __restrict__ out) {
    __shared__ unsigned short sm[2 * 36864];                 // 144 KB
    __shared__ float redS[4][64], redQ[4][64];
    __shared__ float muS[64], rsS[64], n2s[64], n2p[4][64];
    const int t = threadIdx.x, wave = t >> 6, lane = t & 63;
    const int wm = wave >> 2, wn = wave & 3;
    const int laneR = lane & 15;
    const int bm0 = blockIdx.x * 64;

    const int csrc = (t & 3) ^ ((t >> 3) & 3);
    const int akk  = t >> 8, arow = (t >> 2) & 63;
    const unsigned aSrc = (unsigned)(bm0 + arow) * DIM + akk * 32 + csrc * 8;
    const int brow = t >> 2;
    const int slotc = (((lane >> 4) ^ ((lane >> 1) & 3)) & 3) * 8;

    f32x4 acc[2][8] = {};
    f32x4 accN[2] = {};
    bf16x8 ones;
    #pragma unroll
    for (int r = 0; r < 8; r++) ones[r] = (__bf16)1.0f;

    #define G2_STAGE_A(nbuf, kb) {                                          \
        async_copy16(A + aSrc + (kb), sm + (nbuf) * 36864 + t * 8);         \
    }
    #define G2_STAGE_B(nbuf, kk, kb) {                                      \
        unsigned short* d = sm + (nbuf) * 36864 + 4096 + (kk) * 16384 + t * 8; \
        const unsigned short* s0 = B + (size_t)brow * DIM + (kb) + (kk) * 32 + csrc * 8; \
        async_copy16(s0,                 d);                                 \
        async_copy16(s0 + 128 * DIM,     d + 4096);                         \
        async_copy16(s0 + 256 * DIM,     d + 8192);                         \
        async_copy16(s0 + 384 * DIM,     d + 12288);                        \
    }
    #define G2_COMPUTE(cbuf, kk, sel) {                                     \
        const unsigned short* la  = sm + (cbuf) * 36864 + (kk) * 2048;      \
        const unsigned short* lbp = sm + (cbuf) * 36864 + 4096 + (kk) * 16384; \
        bf16x8 af[2], bfr[8];                                               \
        _Pragma("unroll")                                                   \
        for (int i = 0; i < 2; i++)                                         \
            af[i] = *(const bf16x8*)&la[(wm * 32 + i * 16 + laneR) * 32 + slotc]; \
        _Pragma("unroll")                                                   \
        for (int j = 0; j < 8; j++)                                         \
            bfr[j] = *(const bf16x8*)&lbp[(wn * 128 + j * 16 + laneR) * 32 + slotc]; \
        __builtin_amdgcn_s_setprio(1);                                      \
        _Pragma("unroll")                                                   \
        for (int i = 0; i < 2; i++)                                         \
            _Pragma("unroll")                                               \
            for (int j = 0; j < 8; j++)                                     \
                acc[i][j] = __builtin_amdgcn_mfma_f32_16x16x32_bf16(af[i], bfr[j], acc[i][j], 0, 0, 0); \
        if (wn == (sel)) {                                                  \
            _Pragma("unroll")                                               \
            for (int i = 0; i < 2; i++)                                     \
                accN[i] = __builtin_amdgcn_mfma_f32_16x16x32_bf16(af[i], ones, accN[i], 0, 0, 0); \
        }                                                                   \
        __builtin_amdgcn_s_setprio(0);                                      \
    }

    G2_STAGE_A(0, 0); G2_STAGE_B(0, 0, 0); G2_STAGE_B(0, 1, 0);
    asm volatile("s_waitcnt vmcnt(4)" ::: "memory");
    asm volatile("s_barrier" ::: "memory");

    #pragma unroll
    for (int n = 0; n < 15; n++) {
        const int cb = n & 1, nb = cb ^ 1;
        const unsigned kb = (unsigned)(n + 1) * 64;
        G2_STAGE_A(nb, kb); G2_STAGE_B(nb, 0, kb);
        G2_COMPUTE(cb, 0, n & 3);
        asm volatile("s_waitcnt vmcnt(5)" ::: "memory");
        asm volatile("s_barrier" ::: "memory");
        G2_STAGE_B(nb, 1, kb);
        G2_COMPUTE(cb, 1, n & 3);
        asm volatile("s_waitcnt vmcnt(4)" ::: "memory");
        asm volatile("s_barrier" ::: "memory");
    }
    G2_COMPUTE(1, 0, 3);
    asm volatile("s_waitcnt vmcnt(0)" ::: "memory");
    asm volatile("s_barrier" ::: "memory");
    G2_COMPUTE(1, 1, 3);

    #undef G2_STAGE_A
    #undef G2_STAGE_B
    #undef G2_COMPUTE

    // ---- LN epilogue over 64 rows ----
    if (laneR == 0) {
        #pragma unroll
        for (int i = 0; i < 2; i++)
            #pragma unroll
            for (int r = 0; r < 4; r++)
                n2p[wn][wm * 32 + i * 16 + (lane >> 4) * 4 + r] = accN[i][r];
    }
    __syncthreads();
    if (t < 64)
        n2s[t] = n2p[0][t] + n2p[1][t] + n2p[2][t] + n2p[3][t];
    __syncthreads();

    float bvj[8];
    #pragma unroll
    for (int j = 0; j < 8; j++) bvj[j] = bias[wn * 128 + j * 16 + laneR];

    #pragma unroll
    for (int i = 0; i < 2; i++)
        #pragma unroll
        for (int r = 0; r < 4; r++) {
            int rl = wm * 32 + i * 16 + (lane >> 4) * 4 + r;
            float nn = 1.0f / fmaxf(n2s[rl], 1e-24f);
            float s = 0.f, q = 0.f;
            #pragma unroll
            for (int j = 0; j < 8; j++) {
                float val = acc[i][j][r] * nn + bvj[j];
                acc[i][j][r] = val;
                s += val; q += val * val;
            }
            s += __shfl_xor(s, 1, 64); q += __shfl_xor(q, 1, 64);
            s += __shfl_xor(s, 2, 64); q += __shfl_xor(q, 2, 64);
            s += __shfl_xor(s, 4, 64); q += __shfl_xor(q, 4, 64);
            s += __shfl_xor(s, 8, 64); q += __shfl_xor(q, 8, 64);
            if (laneR == 0) { redS[wn][rl] = s; redQ[wn][rl] = q; }
        }
    __syncthreads();
    if (t < 64) {
        float s = redS[0][t] + redS[1][t] + redS[2][t] + redS[3][t];
        float q = redQ[0][t] + redQ[1][t] + redQ[2][t] + redQ[3][t];
        float mu = s * (1.0f / DMODEL);
        float var = q * (1.0f / DMODEL) - mu * mu;
        muS[t] = mu;
        rsS[t] = rsqrtf(var + 1e-5f);
    }
    __syncthreads();
    #pragma unroll
    for (int i = 0; i < 2; i++)
        #pragma unroll
        for (int j = 0; j < 8; j++) {
            int col = wn * 128 + j * 16 + laneR;
            float w = lw[col], bb = lb[col];
            #pragma unroll
            for (int r = 0; r < 4; r++) {
                int rl = wm * 32 + i * 16 + (lane >> 4) * 4 + r;
                out[(size_t)(bm0 + rl) * DMODEL + col] =
                    (acc[i][j][r] - muS[rl]) * rsS[rl] * w + bb;
            }
        }
}

extern "C" void kernel_launch(void* const* d_in, const int* in_sizes, int n_in,
                              void* d_out, int out_size, void* d_ws, size_t ws_size,
                              hipStream_t stream) {
    (void)in_sizes; (void)n_in; (void)out_size; (void)ws_size;
    const float* x     = (const float*)d_in[0];
    const float* W_in  = (const float*)d_in[1];
    const float* b_in  = (const float*)d_in[2];
    const float* W_out = (const float*)d_in[3];
    const float* b_out = (const float*)d_in[4];
    const float* rot   = (const float*)d_in[5];
    const float* ent   = (const float*)d_in[6];
    const float* ln_w  = (const float*)d_in[7];
    const float* ln_b  = (const float*)d_in[8];
    float* out = (float*)d_out;

    char* ws = (char*)d_ws;
    unsigned short* p    = (unsigned short*)ws;                     // [16384][1024] 32 MB
    unsigned short* x_bf = (unsigned short*)(ws + 33554432ull);     // 16 MB
    unsigned short* wtT  = (unsigned short*)(ws + 50331648ull);     // [512][1024] 1 MB
    unsigned short* w2b  = (unsigned short*)(ws + 51380224ull);     // [512][1024] 1 MB
    unsigned short* Ucat = (unsigned short*)(ws + 52428800ull);     // [2048][1024] 4 MB
    unsigned short* W1c  = (unsigned short*)(ws + 56623104ull);     // [2048][512] 2 MB
    float*          b2   = (float*)(ws + 58720256ull);              // [2048] 8 KB
    // high-water ~56 MB

    prep_all_kernel<<<2816, 256, 0, stream>>>(x, x_bf, W_out, w2b, W_in, wtT,
                                              rot, ent, b_in, Ucat, b2);
    fold_kernel<<<dim3(DMODEL / 64, 2 * DIM / 64), 256, 0, stream>>>(Ucat, wtT, W1c);
    gemm1_kernel<<<1024, 512, 0, stream>>>(x_bf, W1c, b2, p);
    gemm2_ln_kernel<<<TOKENS / 64, 512, 0, stream>>>(
        p, w2b, b_out, ln_w, ln_b, out);
}